// Round 11
// baseline (2191.653 us; speedup 1.0000x reference)
//
#include <hip/hip_runtime.h>
#include <hip/hip_fp8.h>
#include <math.h>

#define N_NODES 50000
#define E_EDGES 1600000
#define IN_C    128
#define HID     64
#define OUT_C   40

#define BSH     7            // nodes-per-bucket shift (128)
#define BNODES  128
#define NB      391          // ceil(50000/128)
#define CAP     4864         // tmp entries per bucket (mean 4092, sigma ~64)
#define ACCW    66           // padded LDS acc row stride (floats)
#define TILE    4096         // edges per block in binning pass
#define P1T     512
#define NPB     16           // nodes per block in gemm1

typedef unsigned int uint;
typedef unsigned short ushort;
typedef unsigned char uchar;

// fp8 e4m3 (OCP, gfx950 HW converts). Byte-select must be a literal constant.
__device__ inline uint ftof8(float f) { __hip_fp8_e4m3 t(f); return (uint)t.__x; }
template <int SEL>
__device__ __forceinline__ float f8v(uint dw) {
    return __builtin_amdgcn_cvt_f32_fp8(dw, SEL);
}

// ---------------------------------------------------------------------------
// Pass 1: bin edges by dst bucket (LDS grouping, coalesced run-writes).
// tmp entry: { (dst_local<<16) | src , bits(w_f32) }
// ---------------------------------------------------------------------------
__global__ __launch_bounds__(P1T) void k_bin(const int* __restrict__ ei,
                                             const float* __restrict__ w,
                                             int* __restrict__ bcursor,
                                             uint2* __restrict__ tmp) {
    __shared__ uint2  stage[TILE];            // 32 KB
    __shared__ ushort sbuck[TILE];            // 8 KB
    __shared__ int hist[NB], startb[NB], cursor[NB], baseg[NB];  // 6.3 KB
    __shared__ int sc[P1T];                   // 2 KB
    const int tid = threadIdx.x;
    const int e0  = blockIdx.x * TILE;
    const int n   = min(TILE, E_EDGES - e0);

    for (int i = tid; i < NB; i += P1T) hist[i] = 0;
    __syncthreads();

    for (int i = tid; i < n; i += P1T) {
        int d = ei[E_EDGES + e0 + i];
        atomicAdd(&hist[d >> BSH], 1);
    }
    __syncthreads();

    sc[tid] = (tid < NB) ? hist[tid] : 0;
    __syncthreads();
    for (int off = 1; off < P1T; off <<= 1) {
        int x = (tid >= off) ? sc[tid - off] : 0;
        __syncthreads();
        sc[tid] += x;
        __syncthreads();
    }
    if (tid < NB) {
        int st = sc[tid] - hist[tid];
        startb[tid] = st;
        cursor[tid] = st;
        baseg[tid]  = atomicAdd(&bcursor[tid], hist[tid]);   // reserve global run
    }
    __syncthreads();

    for (int i = tid; i < n; i += P1T) {
        int   s  = ei[e0 + i];
        int   d  = ei[E_EDGES + e0 + i];
        float wv = w[e0 + i];
        int   b  = d >> BSH;
        int pos = atomicAdd(&cursor[b], 1);
        stage[pos] = make_uint2(((uint)(d & (BNODES - 1)) << 16) | (uint)s,
                                __float_as_uint(wv));
        sbuck[pos] = (ushort)b;
    }
    __syncthreads();

    for (int i = tid; i < n; i += P1T) {
        int b = sbuck[i];
        int gpos = baseg[b] + (i - startb[b]);
        tmp[(size_t)b * CAP + gpos] = stage[i];
    }
}

// ---------------------------------------------------------------------------
// dinv[node] = rsqrt(1 + sum_w) per bucket via LDS atomics.
// ---------------------------------------------------------------------------
__global__ __launch_bounds__(256) void k_dinv(const int* __restrict__ bcursor,
                                              const uint2* __restrict__ tmp,
                                              float* __restrict__ dinv) {
    __shared__ float ws[BNODES];
    const int tid = threadIdx.x;
    const int b   = blockIdx.x;
    const int cnt = bcursor[b];
    const uint2* tb = tmp + (size_t)b * CAP;
    if (tid < BNODES) ws[tid] = 0.0f;
    __syncthreads();
    for (int i = tid; i < cnt; i += 256)
        atomicAdd(&ws[tmp[(size_t)b * CAP + i].x >> 16], __uint_as_float(tb[i].y));
    __syncthreads();
    if (tid < BNODES) {
        int node = (b << BSH) + tid;
        if (node < N_NODES) dinv[node] = rsqrtf(1.0f + ws[tid]);
    }
}

// ---------------------------------------------------------------------------
// Layer-1 GEMM: g1 = fp8( dinv[i] * (x[i] @ W1) ). W1 + 16 x-rows in LDS.
// ---------------------------------------------------------------------------
__global__ __launch_bounds__(256) void k_gemm1(const float* __restrict__ x,
                                               const float* __restrict__ W,
                                               const float* __restrict__ dinv,
                                               uchar* __restrict__ g) {
    __shared__ float sW[IN_C * HID];      // 32 KB
    __shared__ float sx[NPB * IN_C];      // 8 KB
    const int tid = threadIdx.x;
    const size_t base = (size_t)blockIdx.x * NPB;

    for (int i = tid; i < (IN_C * HID) / 4; i += 256)
        ((float4*)sW)[i] = ((const float4*)W)[i];
    for (int i = tid; i < (NPB * IN_C) / 4; i += 256)
        ((float4*)sx)[i] = ((const float4*)(x + base * IN_C))[i];
    __syncthreads();

    const int wv = tid >> 6, f = tid & 63;
    for (int nn = 0; nn < 4; ++nn) {
        const int nl = wv * 4 + nn;
        const float* row = &sx[nl * IN_C];
        float acc = 0.0f;
#pragma unroll 8
        for (int k = 0; k < IN_C; k += 4) {
            float4 a = *(const float4*)&row[k];
            acc += a.x * sW[(k + 0) * HID + f] + a.y * sW[(k + 1) * HID + f]
                 + a.z * sW[(k + 2) * HID + f] + a.w * sW[(k + 3) * HID + f];
        }
        const size_t node = base + nl;
        g[node * HID + f] = (uchar)ftof8(dinv[node] * acc);
    }
}

// ---------------------------------------------------------------------------
// Streaming edge pass: block = bucket (128 nodes), acc[128][66] f32 in LDS.
// Per 4-edge wave-iteration: broadcast desc (8B/grp) + dword gather (64B/edge)
// + 4 HW cvt + 4 ds_add_f32. Iterations independent, unroll x2 named.
// ---------------------------------------------------------------------------
__device__ __forceinline__ void stream_edges(const uint2* __restrict__ tb, int cnt,
                                             const uint* __restrict__ gw,
                                             float* __restrict__ acc,
                                             int wid, int grp, int sub) {
    if (cnt <= 0) return;
    for (int e0 = wid * 8; e0 < cnt; e0 += 64) {
        const int eA = e0 + grp;
        const int eB = eA + 4;
        uint2 dA = tb[min(eA, cnt - 1)];
        uint2 dB = tb[min(eB, cnt - 1)];
        float wA = (eA < cnt) ? __uint_as_float(dA.y) : 0.0f;
        float wB = (eB < cnt) ? __uint_as_float(dB.y) : 0.0f;
        uint gA = gw[((dA.x & 0xFFFFu) << 4) + sub];
        uint gB = gw[((dB.x & 0xFFFFu) << 4) + sub];
        float* pA = acc + (dA.x >> 16) * ACCW + sub * 4;
        float* pB = acc + (dB.x >> 16) * ACCW + sub * 4;
        atomicAdd(pA + 0, wA * f8v<0>(gA));
        atomicAdd(pA + 1, wA * f8v<1>(gA));
        atomicAdd(pA + 2, wA * f8v<2>(gA));
        atomicAdd(pA + 3, wA * f8v<3>(gA));
        atomicAdd(pB + 0, wB * f8v<0>(gB));
        atomicAdd(pB + 1, wB * f8v<1>(gB));
        atomicAdd(pB + 2, wB * f8v<2>(gB));
        atomicAdd(pB + 3, wB * f8v<3>(gB));
    }
}

// ---------------------------------------------------------------------------
// A: acc = sum w*g1[src]; act1 = relu(dv*(acc+self)+b1); g2 = fp8(dv*(act1@W2))
// ---------------------------------------------------------------------------
__global__ __launch_bounds__(P1T) void k_aggA(const int* __restrict__ bcursor,
                                              const uint2* __restrict__ tmp,
                                              const uint* __restrict__ gw,
                                              const uchar* __restrict__ gb,
                                              const float* __restrict__ dinv,
                                              const float* __restrict__ bias,
                                              const float* __restrict__ W,
                                              uchar* __restrict__ g_next) {
    __shared__ float acc[BNODES * ACCW];   // 33.8 KB
    __shared__ float sW[HID * HID];        // 16 KB
    __shared__ float sact[8 * HID];        // 2 KB
    const int tid = threadIdx.x;
    const int b   = blockIdx.x;
    const int wid = tid >> 6, lane = tid & 63;
    const int grp = lane >> 4, sub = lane & 15;
    const int cnt = bcursor[b];

    for (int i = tid; i < BNODES * ACCW; i += P1T) acc[i] = 0.0f;
    for (int i = tid; i < HID * HID; i += P1T) sW[i] = W[i];
    __syncthreads();

    stream_edges(tmp + (size_t)b * CAP, cnt, gw, acc, wid, grp, sub);
    __syncthreads();

    const float bl = bias[lane];
    for (int n = wid * 16; n < wid * 16 + 16; ++n) {
        const int node = (b << BSH) + n;
        if (node >= N_NODES) break;
        const float dv = dinv[node];
        float selfv = f8v<0>((uint)gb[(size_t)node * HID + lane]);
        float a = acc[n * ACCW + lane] + selfv;
        sact[wid * HID + lane] = fmaxf(dv * a + bl, 0.0f);
        float dot = 0.0f;
#pragma unroll 4
        for (int k = 0; k < HID; k += 4) {
            float4 av = *(const float4*)&sact[wid * HID + k];
            dot += av.x * sW[(k + 0) * HID + lane] + av.y * sW[(k + 1) * HID + lane]
                 + av.z * sW[(k + 2) * HID + lane] + av.w * sW[(k + 3) * HID + lane];
        }
        g_next[(size_t)node * HID + lane] = (uchar)ftof8(dv * dot);
    }
}

// ---------------------------------------------------------------------------
// B: acc = sum w*g2[src]; h2 = relu(dv*(acc+self)+b2); u2 = fp8(dv*h2)
// ---------------------------------------------------------------------------
__global__ __launch_bounds__(P1T) void k_aggB(const int* __restrict__ bcursor,
                                              const uint2* __restrict__ tmp,
                                              const uint* __restrict__ gw,
                                              const uchar* __restrict__ gb,
                                              const float* __restrict__ dinv,
                                              const float* __restrict__ bias,
                                              uchar* __restrict__ u2b) {
    __shared__ float acc[BNODES * ACCW];   // 33.8 KB
    const int tid = threadIdx.x;
    const int b   = blockIdx.x;
    const int wid = tid >> 6, lane = tid & 63;
    const int grp = lane >> 4, sub = lane & 15;
    const int cnt = bcursor[b];

    for (int i = tid; i < BNODES * ACCW; i += P1T) acc[i] = 0.0f;
    __syncthreads();

    stream_edges(tmp + (size_t)b * CAP, cnt, gw, acc, wid, grp, sub);
    __syncthreads();

    const float bl = bias[lane];
    for (int n = wid * 16; n < wid * 16 + 16; ++n) {
        const int node = (b << BSH) + n;
        if (node >= N_NODES) break;
        const float dv = dinv[node];
        float selfv = f8v<0>((uint)gb[(size_t)node * HID + lane]);
        float a = acc[n * ACCW + lane] + selfv;
        float h = fmaxf(dv * a + bl, 0.0f);
        u2b[(size_t)node * HID + lane] = (uchar)ftof8(dv * h);
    }
}

// ---------------------------------------------------------------------------
// C: acc = sum w*u2[src]; z = acc+self; y = relu(dv*(z@W3)+b3); log_softmax
// ---------------------------------------------------------------------------
__global__ __launch_bounds__(P1T) void k_aggC(const int* __restrict__ bcursor,
                                              const uint2* __restrict__ tmp,
                                              const uint* __restrict__ gw,
                                              const uchar* __restrict__ gb,
                                              const float* __restrict__ dinv,
                                              const float* __restrict__ bias,
                                              const float* __restrict__ W,
                                              float* __restrict__ out) {
    __shared__ float acc[BNODES * ACCW];   // 33.8 KB
    __shared__ float sW[HID * OUT_C];      // 10 KB
    __shared__ float sact[8 * HID];        // 2 KB
    const int tid = threadIdx.x;
    const int b   = blockIdx.x;
    const int wid = tid >> 6, lane = tid & 63;
    const int grp = lane >> 4, sub = lane & 15;
    const int cnt = bcursor[b];

    for (int i = tid; i < BNODES * ACCW; i += P1T) acc[i] = 0.0f;
    for (int i = tid; i < HID * OUT_C; i += P1T) sW[i] = W[i];
    __syncthreads();

    stream_edges(tmp + (size_t)b * CAP, cnt, gw, acc, wid, grp, sub);
    __syncthreads();

    const bool live = lane < OUT_C;
    const float bl = live ? bias[lane] : 0.0f;
    for (int n = wid * 16; n < wid * 16 + 16; ++n) {
        const int node = (b << BSH) + n;
        if (node >= N_NODES) break;
        const float dv = dinv[node];
        float selfv = f8v<0>((uint)gb[(size_t)node * HID + lane]);
        sact[wid * HID + lane] = acc[n * ACCW + lane] + selfv;   // z
        float v = -INFINITY;
        if (live) {
            float dot = 0.0f;
#pragma unroll 4
            for (int k = 0; k < HID; k += 4) {
                float4 av = *(const float4*)&sact[wid * HID + k];
                dot += av.x * sW[(k + 0) * OUT_C + lane] + av.y * sW[(k + 1) * OUT_C + lane]
                     + av.z * sW[(k + 2) * OUT_C + lane] + av.w * sW[(k + 3) * OUT_C + lane];
            }
            v = fmaxf(dv * dot + bl, 0.0f);
        }
        float mx = v;
#pragma unroll
        for (int off = 32; off > 0; off >>= 1) mx = fmaxf(mx, __shfl_xor(mx, off));
        float ex = live ? expf(v - mx) : 0.0f;
        float se = ex;
#pragma unroll
        for (int off = 32; off > 0; off >>= 1) se += __shfl_xor(se, off);
        if (live) out[(size_t)node * OUT_C + lane] = v - mx - logf(se);
    }
}

// ---------------------------------------------------------------------------
// Launch
// ---------------------------------------------------------------------------
extern "C" void kernel_launch(void* const* d_in, const int* in_sizes, int n_in,
                              void* d_out, int out_size, void* d_ws, size_t ws_size,
                              hipStream_t stream) {
    const float* x  = (const float*)d_in[0];
    const int*   ei = (const int*)d_in[1];
    const float* w  = (const float*)d_in[2];
    const float* W1 = (const float*)d_in[3];
    const float* b1 = (const float*)d_in[4];
    const float* W2 = (const float*)d_in[5];
    const float* b2 = (const float*)d_in[6];
    const float* W3 = (const float*)d_in[7];
    const float* b3 = (const float*)d_in[8];
    float* out = (float*)d_out;

    char* ws = (char*)d_ws;
    size_t off = 0;
    auto carve = [&](size_t bytes) {
        char* p = ws + off;
        off += (bytes + 255) & ~(size_t)255;
        return p;
    };
    int*   bcursor = (int*)carve(NB * sizeof(int));
    float* dinv    = (float*)carve(N_NODES * sizeof(float));
    uint2* tmp     = (uint2*)carve((size_t)NB * CAP * sizeof(uint2));   // 15.2 MB
    uchar* g1      = (uchar*)carve((size_t)N_NODES * HID + 256);        // 3.2 MB
    uchar* g2      = (uchar*)carve((size_t)N_NODES * HID + 256);        // 3.2 MB
    uchar* u2      = g1;                     // g1 dead after k_aggA
    (void)ws_size;

    const int nbBin = (E_EDGES + TILE - 1) / TILE;   // 391
    const int nbG1  = N_NODES / NPB;                 // 3125

    (void)hipMemsetAsync(bcursor, 0, NB * sizeof(int), stream);
    k_bin<<<nbBin, P1T, 0, stream>>>(ei, w, bcursor, tmp);
    k_dinv<<<NB, 256, 0, stream>>>(bcursor, tmp, dinv);

    k_gemm1<<<nbG1, 256, 0, stream>>>(x, W1, dinv, g1);
    k_aggA<<<NB, P1T, 0, stream>>>(bcursor, tmp, (const uint*)g1, g1, dinv, b1, W2, g2);
    k_aggB<<<NB, P1T, 0, stream>>>(bcursor, tmp, (const uint*)g2, g2, dinv, b2, u2);
    k_aggC<<<NB, P1T, 0, stream>>>(bcursor, tmp, (const uint*)u2, u2, dinv, b3, W3, out);
}

// Round 12
// 222.455 us; speedup vs baseline: 9.8521x; 9.8521x over previous
//
#include <hip/hip_runtime.h>
#include <hip/hip_fp8.h>
#include <math.h>

#define N_NODES 50000
#define E_EDGES 1600000
#define IN_C    128
#define HID     64
#define OUT_C   40

#define BSH     9            // nodes-per-bucket shift
#define BNODES  512          // 1 << BSH
#define NB      98           // ceil(50000/512)
#define CAP     20480        // tmp entries per bucket
#define PBS     28160        // padded csr stride per bucket
#define TILE    4096         // edges per block in binning pass
#define P1T     512
#define NPB     16           // nodes per block in gemm1

typedef unsigned int uint;
typedef unsigned short ushort;
typedef unsigned char uchar;

__device__ inline ushort f2b(float f) {
    uint u = __float_as_uint(f);
    u += 0x7FFFu + ((u >> 16) & 1u);        // round-to-nearest-even
    return (ushort)(u >> 16);
}
// fp8 e4m3 (OCP, gfx950 HW converts). Byte-select must be a literal constant.
__device__ inline uint ftof8(float f) { __hip_fp8_e4m3 t(f); return (uint)t.__x; }
template <int SEL>
__device__ __forceinline__ float f8v(uint dw) {
    return __builtin_amdgcn_cvt_f32_fp8(dw, SEL);
}

// ---------------------------------------------------------------------------
// Pass 1: bin edges by dst bucket (LDS grouping, coalesced run-writes).
// ---------------------------------------------------------------------------
__global__ __launch_bounds__(P1T) void k_bin(const int* __restrict__ ei,
                                             const float* __restrict__ w,
                                             int* __restrict__ bcursor,
                                             uint2* __restrict__ tmp) {
    __shared__ uint2 stage[TILE];             // 32 KB
    __shared__ unsigned char sbuck[TILE];     // 4 KB
    __shared__ int hist[NB], startb[NB], cursor[NB], baseg[NB];
    __shared__ int sc[128];
    const int tid = threadIdx.x;
    const int e0  = blockIdx.x * TILE;
    const int n   = min(TILE, E_EDGES - e0);

    for (int i = tid; i < NB; i += P1T) hist[i] = 0;
    __syncthreads();

    for (int i = tid; i < n; i += P1T) {
        int d = ei[E_EDGES + e0 + i];
        atomicAdd(&hist[d >> BSH], 1);
    }
    __syncthreads();

    if (tid < 128) sc[tid] = (tid < NB) ? hist[tid] : 0;
    __syncthreads();
    for (int off = 1; off < 128; off <<= 1) {
        int x = 0;
        if (tid < 128 && tid >= off) x = sc[tid - off];
        __syncthreads();
        if (tid < 128) sc[tid] += x;
        __syncthreads();
    }
    if (tid < NB) {
        int st = sc[tid] - hist[tid];
        startb[tid] = st;
        cursor[tid] = st;
        baseg[tid]  = atomicAdd(&bcursor[tid], hist[tid]);   // reserve global run
    }
    __syncthreads();

    for (int i = tid; i < n; i += P1T) {
        int   s  = ei[e0 + i];
        int   d  = ei[E_EDGES + e0 + i];
        float wv = w[e0 + i];
        int   b  = d >> BSH;
        int pos = atomicAdd(&cursor[b], 1);
        stage[pos] = make_uint2(((uint)(d & (BNODES - 1)) << 16) | (uint)s,
                                __float_as_uint(wv));
        sbuck[pos] = (unsigned char)b;
    }
    __syncthreads();

    for (int i = tid; i < n; i += P1T) {
        int b = sbuck[i];
        int gpos = baseg[b] + (i - startb[b]);
        tmp[(size_t)b * CAP + gpos] = stage[i];
    }
}

// ---------------------------------------------------------------------------
// Pass 2: per-bucket CSR finalize, 16-padded rows.
// csr entry: (bf16(w)<<16) | src ; pads are 0. rowinfo=(n16<<24)|start.
// ---------------------------------------------------------------------------
__global__ __launch_bounds__(BNODES) void k_build(const int* __restrict__ bcursor,
                                                  const uint2* __restrict__ tmp,
                                                  uint* __restrict__ rowinfo,
                                                  float* __restrict__ dinv,
                                                  uint* __restrict__ csr) {
    __shared__ int   hist[BNODES];
    __shared__ float wsum[BNODES];
    __shared__ int   sc[BNODES];
    __shared__ int   cur[BNODES];
    const int tid = threadIdx.x;
    const int b   = blockIdx.x;
    const int cnt = bcursor[b];
    const uint2* tb = tmp + (size_t)b * CAP;

    hist[tid] = 0; wsum[tid] = 0.0f;
    __syncthreads();
    for (int i = tid; i < cnt; i += BNODES) {
        uint2 u = tb[i];
        int dl = u.x >> 16;
        atomicAdd(&hist[dl], 1);
        atomicAdd(&wsum[dl], __uint_as_float(u.y));
    }
    __syncthreads();

    const int deg  = hist[tid];
    const int pdeg = (deg + 15) & ~15;
    sc[tid] = pdeg;
    __syncthreads();
    for (int off = 1; off < BNODES; off <<= 1) {
        int x = (tid >= off) ? sc[tid - off] : 0;
        __syncthreads();
        sc[tid] += x;
        __syncthreads();
    }
    const int base = b * PBS + (sc[tid] - pdeg);   // 16-aligned row start
    const int node = (b << BSH) + tid;
    if (node < N_NODES) {
        rowinfo[node] = ((uint)(pdeg >> 4) << 24) | (uint)base;
        dinv[node]    = rsqrtf(1.0f + wsum[tid]);
    }
    cur[tid] = base;
    __syncthreads();

    for (int i = tid; i < cnt; i += BNODES) {
        uint2 u = tb[i];
        int dl = u.x >> 16;
        int pos = atomicAdd(&cur[dl], 1);
        csr[pos] = ((uint)f2b(__uint_as_float(u.y)) << 16) | (u.x & 0xFFFFu);
    }
    for (int i = deg; i < pdeg; ++i) csr[base + i] = 0u;   // zero-weight pads
}

// ---------------------------------------------------------------------------
// Layer-1 GEMM: g1 = fp8( dinv[i] * (x[i] @ W1) ). W1 + 16 x-rows in LDS.
// ---------------------------------------------------------------------------
__global__ __launch_bounds__(256) void k_gemm1(const float* __restrict__ x,
                                               const float* __restrict__ W,
                                               const float* __restrict__ dinv,
                                               uchar* __restrict__ g) {
    __shared__ float sW[IN_C * HID];      // 32 KB
    __shared__ float sx[NPB * IN_C];      // 8 KB
    const int tid = threadIdx.x;
    const size_t base = (size_t)blockIdx.x * NPB;

    for (int i = tid; i < (IN_C * HID) / 4; i += 256)
        ((float4*)sW)[i] = ((const float4*)W)[i];
    for (int i = tid; i < (NPB * IN_C) / 4; i += 256)
        ((float4*)sx)[i] = ((const float4*)(x + base * IN_C))[i];
    __syncthreads();

    const int wv = tid >> 6, f = tid & 63;
    for (int nn = 0; nn < 4; ++nn) {
        const int nl = wv * 4 + nn;
        const float* row = &sx[nl * IN_C];
        float acc = 0.0f;
#pragma unroll 8
        for (int k = 0; k < IN_C; k += 4) {
            float4 a = *(const float4*)&row[k];
            acc += a.x * sW[(k + 0) * HID + f] + a.y * sW[(k + 1) * HID + f]
                 + a.z * sW[(k + 2) * HID + f] + a.w * sW[(k + 3) * HID + f];
        }
        const size_t node = base + nl;
        g[node * HID + f] = (uchar)ftof8(dinv[node] * acc);
    }
}

// ---------------------------------------------------------------------------
// Shared inner loop: aggregate one 64-wide fp8 row per wave.
// grp = lane>>4 (edge slot), sub = lane&15 (dword = 4 fp8 feats).
// 2-deep block unroll: 8 independent gathers in flight per wave.
// Garbage prefetch descriptors are never used for addressing; pad entries
// (src=0,w=0) gather gw[0..15] which is in-bounds.
// ---------------------------------------------------------------------------
__device__ __forceinline__ float4 agg_row64(const uint* __restrict__ csr,
                                            const uint* __restrict__ gw,
                                            uint ri, int node, int lane) {
    const int grp = lane >> 4, sub = lane & 15;
    const int n16 = (int)(ri >> 24);
    float4 acc  = {0.f, 0.f, 0.f, 0.f};
    float4 acc2 = {0.f, 0.f, 0.f, 0.f};
    if (grp == 0) {                       // self loop, weight 1
        uint dw = gw[((uint)node << 4) + sub];
        acc.x = f8v<0>(dw); acc.y = f8v<1>(dw); acc.z = f8v<2>(dw); acc.w = f8v<3>(dw);
    }
    const uint* rp = csr + (ri & 0xFFFFFFu);
    uint d0 = rp[sub];                    // block 0 descriptors
    uint d1 = rp[16 + sub];               // block 1 (garbage if n16<2, unused)
    int blk = 0;
    for (; blk + 2 <= n16; blk += 2) {
        uint dn0 = rp[((blk + 2) << 4) + sub];   // prefetch (slack-covered)
        uint dn1 = rp[((blk + 3) << 4) + sub];
#pragma unroll
        for (int i = 0; i < 4; ++i) {
            uint dj = __shfl(d0, 4 * i + grp);
            uint dk = __shfl(d1, 4 * i + grp);
            float wg0 = __uint_as_float(dj & 0xFFFF0000u);    // bf16 weight
            float wg1 = __uint_as_float(dk & 0xFFFF0000u);
            uint dwa = gw[((dj & 0xFFFFu) << 4) + sub];       // 4 fp8 feats
            uint dwb = gw[((dk & 0xFFFFu) << 4) + sub];
            acc.x  += wg0 * f8v<0>(dwa);
            acc.y  += wg0 * f8v<1>(dwa);
            acc.z  += wg0 * f8v<2>(dwa);
            acc.w  += wg0 * f8v<3>(dwa);
            acc2.x += wg1 * f8v<0>(dwb);
            acc2.y += wg1 * f8v<1>(dwb);
            acc2.z += wg1 * f8v<2>(dwb);
            acc2.w += wg1 * f8v<3>(dwb);
        }
        d0 = dn0; d1 = dn1;
    }
    if (blk < n16) {                      // odd tail block (d0 valid)
#pragma unroll
        for (int i = 0; i < 4; ++i) {
            uint dj = __shfl(d0, 4 * i + grp);
            float wg = __uint_as_float(dj & 0xFFFF0000u);
            uint dw  = gw[((dj & 0xFFFFu) << 4) + sub];
            acc.x += wg * f8v<0>(dw);
            acc.y += wg * f8v<1>(dw);
            acc.z += wg * f8v<2>(dw);
            acc.w += wg * f8v<3>(dw);
        }
    }
    acc.x += acc2.x; acc.y += acc2.y; acc.z += acc2.z; acc.w += acc2.w;
#pragma unroll
    for (int m = 16; m <= 32; m <<= 1) {
        acc.x += __shfl_xor(acc.x, m); acc.y += __shfl_xor(acc.y, m);
        acc.z += __shfl_xor(acc.z, m); acc.w += __shfl_xor(acc.w, m);
    }
    return acc;
}

// ---------------------------------------------------------------------------
// A: aggregate g1 -> act1 = relu(dv*acc+b1) -> GEMM W2 -> g2 = fp8(dv*dot)
// ---------------------------------------------------------------------------
__global__ __launch_bounds__(256) void k_aggA(const uint* __restrict__ rowinfo,
                                              const uint* __restrict__ csr,
                                              const uint* __restrict__ gw,
                                              const float* __restrict__ dinv,
                                              const float* __restrict__ bias,
                                              const float* __restrict__ W,
                                              uchar* __restrict__ g_next) {
    __shared__ float sW[HID * HID];       // 16 KB
    __shared__ float s_act[4][HID];
    const int tid = threadIdx.x;
    for (int i = tid; i < HID * HID; i += 256) sW[i] = W[i];   // sync deferred

    const int wv = tid >> 6, lane = tid & 63;
    const int node = blockIdx.x * 4 + wv;
    const uint ri  = rowinfo[node];
    const float dv = dinv[node];

    float4 acc = agg_row64(csr, gw, ri, node, lane);

    if ((lane >> 4) == 0) {
        const int sub = lane & 15;
        float4 b4 = ((const float4*)bias)[sub];
        float4 r;
        r.x = fmaxf(dv * acc.x + b4.x, 0.f);
        r.y = fmaxf(dv * acc.y + b4.y, 0.f);
        r.z = fmaxf(dv * acc.z + b4.z, 0.f);
        r.w = fmaxf(dv * acc.w + b4.w, 0.f);
        ((float4*)&s_act[wv][0])[sub] = r;
    }
    __syncthreads();
    float dot = 0.0f;
#pragma unroll 4
    for (int k = 0; k < HID; k += 4) {
        float4 a = *(const float4*)&s_act[wv][k];
        dot += a.x * sW[(k + 0) * HID + lane] + a.y * sW[(k + 1) * HID + lane]
             + a.z * sW[(k + 2) * HID + lane] + a.w * sW[(k + 3) * HID + lane];
    }
    g_next[(size_t)node * HID + lane] = (uchar)ftof8(dv * dot);
}

// ---------------------------------------------------------------------------
// B: aggregate g2 -> act2 = relu(dv*acc+b2) -> u2 = fp8(dv*act2). No LDS.
// ---------------------------------------------------------------------------
__global__ __launch_bounds__(256) void k_aggB(const uint* __restrict__ rowinfo,
                                              const uint* __restrict__ csr,
                                              const uint* __restrict__ gw,
                                              const float* __restrict__ dinv,
                                              const float* __restrict__ bias,
                                              uint* __restrict__ u2w) {
    const int tid = threadIdx.x;
    const int wv = tid >> 6, lane = tid & 63;
    const int node = blockIdx.x * 4 + wv;
    const uint ri  = rowinfo[node];
    const float dv = dinv[node];

    float4 acc = agg_row64(csr, gw, ri, node, lane);

    if ((lane >> 4) == 0) {
        const int sub = lane & 15;
        float4 b4 = ((const float4*)bias)[sub];
        uint p0 = ftof8(dv * fmaxf(dv * acc.x + b4.x, 0.f));
        uint p1 = ftof8(dv * fmaxf(dv * acc.y + b4.y, 0.f));
        uint p2 = ftof8(dv * fmaxf(dv * acc.z + b4.z, 0.f));
        uint p3 = ftof8(dv * fmaxf(dv * acc.w + b4.w, 0.f));
        u2w[((uint)node << 4) + sub] = p0 | (p1 << 8) | (p2 << 16) | (p3 << 24);
    }
}

// ---------------------------------------------------------------------------
// C: aggregate u2 -> z (64-wide) -> y = relu(dv*(z@W3)+b3) -> log_softmax
// ---------------------------------------------------------------------------
__global__ __launch_bounds__(256) void k_aggC(const uint* __restrict__ rowinfo,
                                              const uint* __restrict__ csr,
                                              const uint* __restrict__ gw,
                                              const float* __restrict__ dinv,
                                              const float* __restrict__ bias,
                                              const float* __restrict__ W,
                                              float* __restrict__ out) {
    __shared__ float sW[HID * OUT_C];     // 10 KB
    __shared__ float s_z[4][HID];
    const int tid = threadIdx.x;
    for (int i = tid; i < HID * OUT_C; i += 256) sW[i] = W[i];  // sync deferred

    const int wv = tid >> 6, lane = tid & 63;
    const int node = blockIdx.x * 4 + wv;
    const uint ri  = rowinfo[node];
    const float dv = dinv[node];

    float4 acc = agg_row64(csr, gw, ri, node, lane);

    if ((lane >> 4) == 0) ((float4*)&s_z[wv][0])[lane & 15] = acc;
    __syncthreads();

    const bool live = lane < OUT_C;
    float v = -INFINITY;
    if (live) {
        float dot = 0.0f;
#pragma unroll 4
        for (int k = 0; k < HID; k += 4) {
            float4 a = *(const float4*)&s_z[wv][k];
            dot += a.x * sW[(k + 0) * OUT_C + lane] + a.y * sW[(k + 1) * OUT_C + lane]
                 + a.z * sW[(k + 2) * OUT_C + lane] + a.w * sW[(k + 3) * OUT_C + lane];
        }
        v = fmaxf(dv * dot + bias[lane], 0.0f);
    }
    float mx = v;
#pragma unroll
    for (int off = 32; off > 0; off >>= 1) mx = fmaxf(mx, __shfl_xor(mx, off));
    float ex = live ? expf(v - mx) : 0.0f;
    float se = ex;
#pragma unroll
    for (int off = 32; off > 0; off >>= 1) se += __shfl_xor(se, off);
    if (live) out[(size_t)node * OUT_C + lane] = v - mx - logf(se);
}

// ---------------------------------------------------------------------------
// Launch
// ---------------------------------------------------------------------------
extern "C" void kernel_launch(void* const* d_in, const int* in_sizes, int n_in,
                              void* d_out, int out_size, void* d_ws, size_t ws_size,
                              hipStream_t stream) {
    const float* x  = (const float*)d_in[0];
    const int*   ei = (const int*)d_in[1];
    const float* w  = (const float*)d_in[2];
    const float* W1 = (const float*)d_in[3];
    const float* b1 = (const float*)d_in[4];
    const float* W2 = (const float*)d_in[5];
    const float* b2 = (const float*)d_in[6];
    const float* W3 = (const float*)d_in[7];
    const float* b3 = (const float*)d_in[8];
    float* out = (float*)d_out;

    char* ws = (char*)d_ws;
    size_t off = 0;
    auto carve = [&](size_t bytes) {
        char* p = ws + off;
        off += (bytes + 255) & ~(size_t)255;
        return p;
    };
    int*   bcursor = (int*)carve(NB * sizeof(int));
    uint*  rowinfo = (uint*)carve(N_NODES * sizeof(uint));
    float* dinv    = (float*)carve(N_NODES * sizeof(float));
    uint*  csr     = (uint*)carve(((size_t)NB * PBS + 64) * sizeof(uint));  // 11.0 MB
    uint2* tmp     = (uint2*)carve((size_t)NB * CAP * sizeof(uint2) + 256); // 16.05 MB
    // tmp dead after k_build; reuse for fp8 activation tables (64 B rows)
    uchar* g1 = (uchar*)tmp;                         // 3.2 MB
    uchar* g2 = g1 + (size_t)N_NODES * HID;          // 3.2 MB
    uchar* u2 = g1;                                  // g1 dead after k_aggA
    (void)ws_size;

    const int nbBin = (E_EDGES + TILE - 1) / TILE;   // 391
    const int nbN4  = N_NODES / 4;                   // 12500
    const int nbG1  = N_NODES / NPB;                 // 3125

    (void)hipMemsetAsync(bcursor, 0, NB * sizeof(int), stream);
    k_bin<<<nbBin, P1T, 0, stream>>>(ei, w, bcursor, tmp);
    k_build<<<NB, BNODES, 0, stream>>>(bcursor, tmp, rowinfo, dinv, csr);

    k_gemm1<<<nbG1, 256, 0, stream>>>(x, W1, dinv, g1);
    k_aggA<<<nbN4, 256, 0, stream>>>(rowinfo, csr, (const uint*)g1, dinv, b1, W2, g2);
    k_aggB<<<nbN4, 256, 0, stream>>>(rowinfo, csr, (const uint*)g2, dinv, b2, (uint*)u2);
    k_aggC<<<nbN4, 256, 0, stream>>>(rowinfo, csr, (const uint*)u2, dinv, b3, W3, out);
}